// Round 11
// baseline (386.281 us; speedup 1.0000x reference)
//
#include <hip/hip_runtime.h>
#include <hip/hip_bf16.h>
#include <math.h>

#define N_NODES 50000
#define E_EDGES 800000
#define ET (E_EDGES + N_NODES)   // edges + self loops = 850000
#define NBLK_SCAN ((N_NODES + 255) / 256)   // 196
#define MPAD 50048               // 782 * 64
#define NPB_T1 16                // nodes per block in transform1
#define WROWS 160                // W2T rows: 128 h2 + 8 attn-dot + 24 pad

typedef __attribute__((ext_vector_type(4))) float f32x4;
typedef __attribute__((ext_vector_type(8))) _Float16 half8;
typedef __attribute__((ext_vector_type(2))) _Float16 half2v;

// ---------------- CSR build ----------------

__global__ void zero_int_kernel(int* __restrict__ p, int n) {
    int i = blockIdx.x * blockDim.x + threadIdx.x;
    if (i < n) p[i] = 0;
}

__global__ void hist_kernel(const int* __restrict__ ei, int* __restrict__ cnt) {
    int e = blockIdx.x * blockDim.x + threadIdx.x;
    if (e < ET) {
        int d = (e < E_EDGES) ? ei[E_EDGES + e] : (e - E_EDGES);
        atomicAdd(&cnt[d], 1);
    }
}

__global__ void scan1_kernel(const int* __restrict__ cnt, int* __restrict__ rp,
                             int* __restrict__ bsum) {
    __shared__ int s[256];
    int i = blockIdx.x * 256 + threadIdx.x;
    int v = (i < N_NODES) ? cnt[i] : 0;
    s[threadIdx.x] = v;
    __syncthreads();
    for (int off = 1; off < 256; off <<= 1) {
        int t = (threadIdx.x >= off) ? s[threadIdx.x - off] : 0;
        __syncthreads();
        s[threadIdx.x] += t;
        __syncthreads();
    }
    if (i < N_NODES) rp[i + 1] = s[threadIdx.x];
    if (threadIdx.x == 255) bsum[blockIdx.x] = s[255];
}

__global__ void scan2_kernel(int* __restrict__ bsum, int nb) {
    __shared__ int s[256];
    int v = (threadIdx.x < nb) ? bsum[threadIdx.x] : 0;
    s[threadIdx.x] = v;
    __syncthreads();
    for (int off = 1; off < 256; off <<= 1) {
        int t = (threadIdx.x >= off) ? s[threadIdx.x - off] : 0;
        __syncthreads();
        s[threadIdx.x] += t;
        __syncthreads();
    }
    if (threadIdx.x < nb) bsum[threadIdx.x] = (threadIdx.x == 0) ? 0 : s[threadIdx.x - 1];
}

__global__ void scan3_kernel(int* __restrict__ rp, const int* __restrict__ bsum,
                             int* __restrict__ cursor) {
    int i = blockIdx.x * 256 + threadIdx.x;
    if (i == 0) rp[0] = 0;
    if (i < N_NODES) {
        int incl = rp[i + 1] + bsum[i >> 8];
        rp[i + 1] = incl;
        cursor[i] = incl - cursor[i];
    }
}

__global__ void fill_kernel(const int* __restrict__ ei, int* __restrict__ cursor,
                            int* __restrict__ col) {
    int e = blockIdx.x * blockDim.x + threadIdx.x;
    if (e < ET) {
        int s_, d;
        if (e < E_EDGES) { s_ = ei[e]; d = ei[E_EDGES + e]; }
        else             { s_ = e - E_EDGES; d = s_; }
        int p = atomicAdd(&cursor[d], 1);
        col[p] = s_;
    }
}

// ---------------- layer-1 specialized path (aggregate in x-space, K=9) ----------------

__global__ void prep_attn1_kernel(const float* __restrict__ W1,
                                  const float* __restrict__ a1s,
                                  const float* __restrict__ a1d,
                                  float* __restrict__ M) {
    int t = threadIdx.x;
    if (t < 144) {
        int which = t / 72, idx = t % 72, k = idx / 8, h = idx % 8;
        const float* a = which ? a1d : a1s;
        float s = 0.f;
        for (int c = 0; c < 64; c++) s += W1[k * 512 + h * 64 + c] * a[h * 64 + c];
        M[t] = s;
    }
}

__global__ void es_ed1_kernel(const float* __restrict__ x, const float* __restrict__ M,
                              float* __restrict__ es, float* __restrict__ ed) {
    int n = blockIdx.x * blockDim.x + threadIdx.x;
    if (n >= N_NODES) return;
    float xr[9];
#pragma unroll
    for (int k = 0; k < 9; k++) xr[k] = x[(size_t)n * 9 + k];
#pragma unroll
    for (int h = 0; h < 8; h++) {
        float s1 = 0.f, s2 = 0.f;
#pragma unroll
        for (int k = 0; k < 9; k++) {
            s1 += xr[k] * M[k * 8 + h];
            s2 += xr[k] * M[72 + k * 8 + h];
        }
        es[(size_t)n * 8 + h] = s1;
        ed[(size_t)n * 8 + h] = s2;
    }
}

// per-dst: online softmax over in-edges + aggregate x rows (9 floats) per head.
// LDS layout: s_w/s_es e-major with odd/12 stride (conflict-free), float4 es staging,
// 4-deep independent accumulators in the gather.
__global__ __launch_bounds__(128) void agg1_kernel(const float* __restrict__ x,
        const int* __restrict__ rp, const int* __restrict__ col,
        const float* __restrict__ es, const float* __restrict__ ed,
        float* __restrict__ aggx) {
    __shared__ int   s_src[64];
    __shared__ float s_x[64][9];
    __shared__ float s_es[64][12];   // 48B rows: float4-aligned, 2-way banks max
    __shared__ float s_w[64][9];     // e-major, odd stride -> spread banks
    __shared__ float s_m[8], s_den[8], s_scale[8], s_ed[8];
    int n = blockIdx.x, tid = threadIdx.x;
    int start = rp[n], end = rp[n + 1];
    if (tid < 8) { s_m[tid] = -INFINITY; s_den[tid] = 0.f; s_ed[tid] = ed[(size_t)n * 8 + tid]; }
    __syncthreads();
    int ghh = tid >> 4, glane = tid & 15;
    int hh = tid / 9, k = tid - hh * 9;   // valid for tid < 72
    float p0 = 0.f, p1 = 0.f, p2 = 0.f, p3 = 0.f;
    for (int cs = start; cs < end; cs += 64) {
        int cnt = min(64, end - cs);
        if (tid < cnt) s_src[tid] = col[cs + tid];
        __syncthreads();
        for (int q = tid; q < cnt * 9; q += 128) {
            int e = q / 9, kk = q - e * 9;
            s_x[e][kk] = x[(size_t)s_src[e] * 9 + kk];
        }
        for (int q = tid; q < cnt * 2; q += 128) {
            int e = q >> 1, h4 = (q & 1) * 4;
            *(float4*)&s_es[e][h4] = *(const float4*)&es[(size_t)s_src[e] * 8 + h4];
        }
        __syncthreads();
        float lmax = -INFINITY;
        for (int e = glane; e < cnt; e += 16) {
            float l = s_es[e][ghh] + s_ed[ghh];
            l = (l > 0.f) ? l : 0.2f * l;
            s_w[e][ghh] = l;
            lmax = fmaxf(lmax, l);
        }
#pragma unroll
        for (int off = 8; off > 0; off >>= 1) lmax = fmaxf(lmax, __shfl_xor(lmax, off));
        float mold = s_m[ghh];
        float nm = fmaxf(mold, lmax);
        float fac = __expf(mold - nm);
        float psum = 0.f;
        for (int e = glane; e < cnt; e += 16) {
            float w = __expf(s_w[e][ghh] - nm);
            s_w[e][ghh] = w;
            psum += w;
        }
#pragma unroll
        for (int off = 8; off > 0; off >>= 1) psum += __shfl_xor(psum, off);
        if (glane == 0) { s_den[ghh] = s_den[ghh] * fac + psum; s_m[ghh] = nm; s_scale[ghh] = fac; }
        __syncthreads();
        if (tid < 72) {
            float fac2 = s_scale[hh];
            p0 *= fac2; p1 *= fac2; p2 *= fac2; p3 *= fac2;
            int e = 0;
            for (; e + 4 <= cnt; e += 4) {
                p0 += s_w[e][hh]     * s_x[e][k];
                p1 += s_w[e + 1][hh] * s_x[e + 1][k];
                p2 += s_w[e + 2][hh] * s_x[e + 2][k];
                p3 += s_w[e + 3][hh] * s_x[e + 3][k];
            }
            for (; e < cnt; e++) p0 += s_w[e][hh] * s_x[e][k];
        }
        __syncthreads();
    }
    if (tid < 72) {
        aggx[(size_t)n * 72 + tid] = (p0 + p1 + p2 + p3) / s_den[hh];
    }
}

// out = ELU(BN( aggx@W1 + b1 )) -> fp16 [MPAD,512].
__global__ __launch_bounds__(256) void transform1_kernel(const float* __restrict__ aggx,
        const float* __restrict__ W1, const float* __restrict__ b1,
        const float* __restrict__ g1, const float* __restrict__ be1,
        _Float16* __restrict__ Af) {
    __shared__ float s_a[NPB_T1 * 72];
    int tid = threadIdx.x;
    int n0 = blockIdx.x * NPB_T1;
    int nn = min(NPB_T1, N_NODES - n0);
    for (int q = tid; q < nn * 72; q += 256) s_a[q] = aggx[(size_t)n0 * 72 + q];
    int c0 = tid * 2;
    int hh = c0 >> 6;
    float2 wv[9];
#pragma unroll
    for (int k = 0; k < 9; k++) wv[k] = *(const float2*)&W1[k * 512 + c0];
    float2 bv = *(const float2*)&b1[c0];
    float2 gv = *(const float2*)&g1[c0];
    float2 ev = *(const float2*)&be1[c0];
    float gs0 = gv.x / sqrtf(1.00001f), gs1 = gv.y / sqrtf(1.00001f);
    __syncthreads();
    for (int i = 0; i < nn; i++) {
        const float* ar = &s_a[i * 72 + hh * 9];
        float v0 = bv.x, v1 = bv.y;
#pragma unroll
        for (int k = 0; k < 9; k++) { float a = ar[k]; v0 += a * wv[k].x; v1 += a * wv[k].y; }
        v0 = v0 * gs0 + ev.x;
        v1 = v1 * gs1 + ev.y;
        v0 = (v0 > 0.f) ? v0 : expm1f(v0);
        v1 = (v1 > 0.f) ? v1 : expm1f(v1);
        half2v hp;
        hp[0] = (_Float16)v0;
        hp[1] = (_Float16)v1;
        *(half2v*)&Af[(size_t)(n0 + i) * 512 + c0] = hp;
    }
}

// prep: W2^T fp16 [WROWS][512] (rows 0..127 = W2 cols; 128..131 = W2@a2s heads;
// 132..135 = W2@a2d heads).
__global__ void prep2_kernel(const float* __restrict__ W2,
                             const float* __restrict__ a2s, const float* __restrict__ a2d,
                             _Float16* __restrict__ WT) {
    int t = blockIdx.x * 256 + threadIdx.x;
    if (t < 65536) {
        int k = t >> 7, c = t & 127;
        WT[(size_t)c * 512 + k] = (_Float16)W2[t];
    } else if (t < 65536 + 4096) {
        int q = t - 65536;
        int hd8 = q >> 9, k = q & 511;
        const float* a = (hd8 < 4) ? a2s : a2d;
        int hd = hd8 & 3;
        float s = 0.f;
#pragma unroll
        for (int c = 0; c < 32; c++) s += W2[k * 128 + hd * 32 + c] * a[hd * 32 + c];
        WT[(size_t)(128 + hd8) * 512 + k] = (_Float16)s;
    }
}

// ---------------- layer-2 GEMM via fp16 MFMA, fused attn-dot columns ----------------
// 64-row tiles (782 blocks -> ~3 resident/CU): C[N,136] = A[N,512] @ W2aug;
// cols 0..127 -> h2 fp16, 128..131 -> es, 132..135 -> ed.

__global__ __launch_bounds__(256) void gemm2_mfma_kernel(
        const _Float16* __restrict__ A, const _Float16* __restrict__ WT,
        _Float16* __restrict__ h2, float* __restrict__ es, float* __restrict__ ed) {
    __shared__ _Float16 ldsA[64 * 64];
    __shared__ _Float16 ldsW[WROWS * 64];
    int tid = threadIdx.x;
    int wv = tid >> 6;
    int lane = tid & 63;
    int lrow = lane & 15, kgrp = lane >> 4;
    int m0 = blockIdx.x * 64;

    f32x4 acc[9];
#pragma unroll
    for (int n = 0; n < 9; n++) acc[n] = (f32x4){0.f, 0.f, 0.f, 0.f};

    for (int kk = 0; kk < 512; kk += 64) {
#pragma unroll
        for (int i = 0; i < 2; i++) {
            int gid = tid + 256 * i;
            int row = gid >> 3, kg = gid & 7;
            half8 v = *(const half8*)(A + (size_t)(m0 + row) * 512 + kk + kg * 8);
            *(half8*)(ldsA + row * 64 + ((kg ^ (row & 7)) << 3)) = v;
        }
#pragma unroll
        for (int i = 0; i < 5; i++) {
            int gid = tid + 256 * i;
            int row = gid >> 3, kg = gid & 7;
            half8 v = *(const half8*)(WT + (size_t)row * 512 + kk + kg * 8);
            *(half8*)(ldsW + row * 64 + ((kg ^ (row & 7)) << 3)) = v;
        }
        __syncthreads();
#pragma unroll
        for (int ks = 0; ks < 2; ks++) {
            int kg = ks * 4 + kgrp;
            int row = wv * 16 + lrow;
            half8 af = *(const half8*)(ldsA + row * 64 + ((kg ^ (row & 7)) << 3));
#pragma unroll
            for (int n = 0; n < 9; n++) {
                int colr = n * 16 + lrow;
                half8 wf = *(const half8*)(ldsW + colr * 64 + ((kg ^ (colr & 7)) << 3));
                acc[n] = __builtin_amdgcn_mfma_f32_16x16x32_f16(af, wf, acc[n], 0, 0, 0);
            }
        }
        __syncthreads();
    }
#pragma unroll
    for (int r = 0; r < 4; r++) {
        int row = m0 + wv * 16 + (lane >> 4) * 4 + r;
        if (row < N_NODES) {
#pragma unroll
            for (int n = 0; n < 8; n++)
                h2[(size_t)row * 128 + n * 16 + lrow] = (_Float16)acc[n][r];
            if (lrow < 4)      es[(size_t)row * 4 + lrow]     = acc[8][r];
            else if (lrow < 8) ed[(size_t)row * 4 + lrow - 4] = acc[8][r];
        }
    }
}

// ---------------- layer-2 agg (1 wave) + fused layer-3 GEMM + attn dots ----------------
// FROZEN (R8 regression isolation: epilogue rewrite cost +51us at identical counters).

__global__ __launch_bounds__(64) void agg2_fused_kernel(
        const _Float16* __restrict__ hin,
        const int* __restrict__ rp, const int* __restrict__ col,
        const float* __restrict__ es, const float* __restrict__ ed,
        const float* __restrict__ b2, const float* __restrict__ g2,
        const float* __restrict__ be2,
        const float* __restrict__ W3, const float* __restrict__ a3s,
        const float* __restrict__ a3d,
        _Float16* __restrict__ h3, float* __restrict__ es3, float* __restrict__ ed3) {
    constexpr int H = 4, HC = 128, LPH = 16, G = 4, CH = 64;
    __shared__ int   s_src[CH];
    __shared__ float s_w[H][CH];
    __shared__ float s_red[G][HC];
    __shared__ float s_res[HC];
    __shared__ float s_m[H], s_den[H], s_scale[H], s_ed[H];

    int n = blockIdx.x, tid = threadIdx.x;
    int start = rp[n], end = rp[n + 1];
    if (tid < H) { s_m[tid] = -INFINITY; s_den[tid] = 0.f; s_ed[tid] = ed[(size_t)n * H + tid]; }
    __syncthreads();

    int ghh = tid >> 4, glane = tid & 15;      // softmax: 16 lanes per head
    int g = tid >> 4, rl = tid & 15;           // gather: group g, row-lane rl
    int hh2 = rl >> 2;                         // head owning channels rl*8..rl*8+7
    float a0[8], a1[8];
#pragma unroll
    for (int j = 0; j < 8; j++) { a0[j] = 0.f; a1[j] = 0.f; }

    for (int cs = start; cs < end; cs += CH) {
        int cnt = min(CH, end - cs);
        if (tid < cnt) s_src[tid] = col[cs + tid];
        __syncthreads();

        {
            float lmax = -INFINITY;
            for (int e = glane; e < cnt; e += LPH) {
                float l = es[(size_t)s_src[e] * H + ghh] + s_ed[ghh];
                l = (l > 0.f) ? l : 0.2f * l;
                s_w[ghh][e] = l;
                lmax = fmaxf(lmax, l);
            }
#pragma unroll
            for (int off = 8; off > 0; off >>= 1) lmax = fmaxf(lmax, __shfl_xor(lmax, off));
            float mold = s_m[ghh];
            float nm = fmaxf(mold, lmax);
            float fac = __expf(mold - nm);
            float psum = 0.f;
            for (int e = glane; e < cnt; e += LPH) {
                float w = __expf(s_w[ghh][e] - nm);
                s_w[ghh][e] = w;
                psum += w;
            }
#pragma unroll
            for (int off = 8; off > 0; off >>= 1) psum += __shfl_xor(psum, off);
            if (glane == 0) { s_den[ghh] = s_den[ghh] * fac + psum; s_m[ghh] = nm; s_scale[ghh] = fac; }
        }
        __syncthreads();

        {
            float fac = s_scale[hh2];
#pragma unroll
            for (int j = 0; j < 8; j++) a0[j] *= fac;
            int e = g;
            for (; e + G < cnt; e += 2 * G) {
                float w0 = s_w[hh2][e];
                float w1 = s_w[hh2][e + G];
                half8 v0 = *(const half8*)&hin[(size_t)s_src[e] * HC + rl * 8];
                half8 v1 = *(const half8*)&hin[(size_t)s_src[e + G] * HC + rl * 8];
#pragma unroll
                for (int j = 0; j < 8; j++) a0[j] += w0 * (float)v0[j];
#pragma unroll
                for (int j = 0; j < 8; j++) a1[j] += w1 * (float)v1[j];
            }
            if (e < cnt) {
                float w0 = s_w[hh2][e];
                half8 v0 = *(const half8*)&hin[(size_t)s_src[e] * HC + rl * 8];
#pragma unroll
                for (int j = 0; j < 8; j++) a0[j] += w0 * (float)v0[j];
            }
        }
        __syncthreads();
    }

#pragma unroll
    for (int j = 0; j < 8; j++) s_red[g][rl * 8 + j] = a0[j] + a1[j];
    __syncthreads();

    // h2' row: 2 channels per thread, BN+ELU into s_res
    const float rsq = 0.99999499f;   // 1/sqrt(1+1e-5)
#pragma unroll
    for (int half = 0; half < 2; half++) {
        int c = tid + half * 64;
        float r = s_red[0][c] + s_red[1][c] + s_red[2][c] + s_red[3][c];
        r /= s_den[c >> 5];
        r += b2[c];
        r = r * (g2[c] * rsq) + be2[c];
        r = (r > 0.f) ? r : expm1f(r);
        s_res[c] = r;
    }
    __syncthreads();

    // h3 = s_res @ W3 ([128][32], L1-hot): lane (j, half) sums 64 terms, pair-reduce
    int halfk = tid >> 5, j = tid & 31;
    float v = 0.f;
#pragma unroll 16
    for (int c = halfk * 64; c < halfk * 64 + 64; c++) v += s_res[c] * W3[c * 32 + j];
    v += __shfl_xor(v, 32);
    if (tid < 32) h3[(size_t)n * 32 + j] = (_Float16)v;
    // es3/ed3 dots over 32 channels (both halves hold identical v per j)
    float p1 = v * a3s[j], p2 = v * a3d[j];
#pragma unroll
    for (int off = 16; off > 0; off >>= 1) {
        p1 += __shfl_xor(p1, off);
        p2 += __shfl_xor(p2, off);
    }
    if (tid == 0) { es3[n] = p1; ed3[n] = p2; }
}

// ---------------- layer-3 agg (1 wave) + fused head ----------------

__global__ __launch_bounds__(64) void agg3_fused_kernel(
        const _Float16* __restrict__ hin,
        const int* __restrict__ rp, const int* __restrict__ col,
        const float* __restrict__ es3, const float* __restrict__ ed3,
        const float* __restrict__ b3, const float* __restrict__ g3,
        const float* __restrict__ be3,
        const float* __restrict__ Wh, const float* __restrict__ bh,
        float* __restrict__ out) {
    constexpr int G = 16, CH = 64;
    __shared__ int   s_src[CH];
    __shared__ float s_w[CH];
    __shared__ float s_red[G][36];
    __shared__ float s_m1, s_den1, s_scale1, s_ed1;

    int n = blockIdx.x, tid = threadIdx.x;
    int start = rp[n], end = rp[n + 1];
    if (tid == 0) { s_m1 = -INFINITY; s_den1 = 0.f; s_ed1 = ed3[n]; }
    __syncthreads();

    int g = tid >> 2, rl = tid & 3;
    float a0[8], a1[8];
#pragma unroll
    for (int j = 0; j < 8; j++) { a0[j] = 0.f; a1[j] = 0.f; }

    for (int cs = start; cs < end; cs += CH) {
        int cnt = min(CH, end - cs);
        if (tid < cnt) s_src[tid] = col[cs + tid];
        __syncthreads();

        float lmax = -INFINITY;
        float l = 0.f;
        if (tid < cnt) {
            l = es3[s_src[tid]] + s_ed1;
            l = (l > 0.f) ? l : 0.2f * l;
            lmax = l;
        }
#pragma unroll
        for (int off = 32; off > 0; off >>= 1) lmax = fmaxf(lmax, __shfl_xor(lmax, off));
        float mold = s_m1;
        float nm = fmaxf(mold, lmax);
        float fac = __expf(mold - nm);
        float w = 0.f;
        if (tid < cnt) {
            w = __expf(l - nm);
            s_w[tid] = w;
        }
        float psum = w;
#pragma unroll
        for (int off = 32; off > 0; off >>= 1) psum += __shfl_xor(psum, off);
        if (tid == 0) { s_den1 = s_den1 * fac + psum; s_m1 = nm; s_scale1 = fac; }
        __syncthreads();

        {
#pragma unroll
            for (int j = 0; j < 8; j++) a0[j] *= fac;
            int e = g;
            for (; e + G < cnt; e += 2 * G) {
                float w0 = s_w[e];
                float w1 = s_w[e + G];
                half8 v0 = *(const half8*)&hin[(size_t)s_src[e] * 32 + rl * 8];
                half8 v1 = *(const half8*)&hin[(size_t)s_src[e + G] * 32 + rl * 8];
#pragma unroll
                for (int j = 0; j < 8; j++) a0[j] += w0 * (float)v0[j];
#pragma unroll
                for (int j = 0; j < 8; j++) a1[j] += w1 * (float)v1[j];
            }
            if (e < cnt) {
                float w0 = s_w[e];
                half8 v0 = *(const half8*)&hin[(size_t)s_src[e] * 32 + rl * 8];
#pragma unroll
                for (int j = 0; j < 8; j++) a0[j] += w0 * (float)v0[j];
            }
        }
        __syncthreads();
    }

#pragma unroll
    for (int j = 0; j < 8; j++) s_red[g][rl * 8 + j] = a0[j] + a1[j];
    __syncthreads();

    const float rsq = 0.99999499f;
    float p = 0.f;
    if (tid < 32) {
        float r = 0.f;
#pragma unroll
        for (int q = 0; q < G; q++) r += s_red[q][tid];
        r /= s_den1;
        r += b3[tid];
        r = r * (g3[tid] * rsq) + be3[tid];
        r = (r > 0.f) ? r : expm1f(r);
        p = r * Wh[tid];
    }
#pragma unroll
    for (int off = 16; off > 0; off >>= 1) p += __shfl_xor(p, off);
    if (tid == 0) out[n] = p + bh[0];
}

// ---------------- launch ----------------

extern "C" void kernel_launch(void* const* d_in, const int* in_sizes, int n_in,
                              void* d_out, int out_size, void* d_ws, size_t ws_size,
                              hipStream_t stream) {
    const float* x   = (const float*)d_in[0];
    const int*   ei  = (const int*)d_in[1];
    const float* W1  = (const float*)d_in[2];
    const float* a1s = (const float*)d_in[3];
    const float* a1d = (const float*)d_in[4];
    const float* b1  = (const float*)d_in[5];
    const float* W2  = (const float*)d_in[6];
    const float* a2s = (const float*)d_in[7];
    const float* a2d = (const float*)d_in[8];
    const float* b2  = (const float*)d_in[9];
    const float* W3  = (const float*)d_in[10];
    const float* a3s = (const float*)d_in[11];
    const float* a3d = (const float*)d_in[12];
    const float* b3  = (const float*)d_in[13];
    const float* g1  = (const float*)d_in[14];
    const float* be1 = (const float*)d_in[15];
    const float* g2  = (const float*)d_in[16];
    const float* be2 = (const float*)d_in[17];
    const float* g3  = (const float*)d_in[18];
    const float* be3 = (const float*)d_in[19];
    const float* Wh  = (const float*)d_in[20];
    const float* bh  = (const float*)d_in[21];
    float* out = (float*)d_out;

    char* ws = (char*)d_ws;
    size_t off = 0;
    auto alloc = [&](size_t bytes) -> void* {
        void* p = ws + off;
        off += (bytes + 255) & ~(size_t)255;
        return p;
    };
    int*   row_ptr = (int*)alloc((N_NODES + 1) * sizeof(int));
    int*   cursor  = (int*)alloc((N_NODES + 1) * sizeof(int));
    int*   bsum    = (int*)alloc(256 * sizeof(int));
    int*   col_src = (int*)alloc((size_t)ET * sizeof(int));
    float* es      = (float*)alloc((size_t)N_NODES * 8 * sizeof(float));
    float* ed      = (float*)alloc((size_t)N_NODES * 8 * sizeof(float));
    float* es3     = (float*)alloc((size_t)N_NODES * sizeof(float));
    float* ed3     = (float*)alloc((size_t)N_NODES * sizeof(float));
    float* aggx    = (float*)alloc((size_t)N_NODES * 72 * sizeof(float));
    _Float16* h2h  = (_Float16*)alloc((size_t)N_NODES * 128 * sizeof(_Float16));
    _Float16* h3h  = (_Float16*)alloc((size_t)N_NODES * 32 * sizeof(_Float16));
    _Float16* Af   = (_Float16*)alloc((size_t)MPAD * 512 * sizeof(_Float16));
    _Float16* WT   = (_Float16*)alloc((size_t)WROWS * 512 * sizeof(_Float16));
    float* M1 = (float*)(ws + ((ws_size - 1024) & ~(size_t)255));

    // ---- CSR build (dst-sorted), shared by all three layers ----
    zero_int_kernel<<<(N_NODES + 1 + 255) / 256, 256, 0, stream>>>(cursor, N_NODES + 1);
    hist_kernel<<<(ET + 255) / 256, 256, 0, stream>>>(ei, cursor);
    scan1_kernel<<<NBLK_SCAN, 256, 0, stream>>>(cursor, row_ptr, bsum);
    scan2_kernel<<<1, 256, 0, stream>>>(bsum, NBLK_SCAN);
    scan3_kernel<<<NBLK_SCAN, 256, 0, stream>>>(row_ptr, bsum, cursor);
    fill_kernel<<<(ET + 255) / 256, 256, 0, stream>>>(ei, cursor, col_src);

    // ---- layer 1: GAT(9 -> 8x64, concat) + BN + ELU, aggregated in x-space ----
    prep_attn1_kernel<<<1, 256, 0, stream>>>(W1, a1s, a1d, M1);
    es_ed1_kernel<<<(N_NODES + 255) / 256, 256, 0, stream>>>(x, M1, es, ed);
    agg1_kernel<<<N_NODES, 128, 0, stream>>>(x, row_ptr, col_src, es, ed, aggx);
    transform1_kernel<<<(N_NODES + NPB_T1 - 1) / NPB_T1, 256, 0, stream>>>(aggx, W1, b1, g1, be1, Af);

    // ---- layer 2: fp16 MFMA GEMM with fused attn-dot cols, then agg (+layer-3 prep) ----
    prep2_kernel<<<288, 256, 0, stream>>>(W2, a2s, a2d, WT);
    gemm2_mfma_kernel<<<MPAD / 64, 256, 0, stream>>>(Af, WT, h2h, es, ed);
    agg2_fused_kernel<<<N_NODES, 64, 0, stream>>>(h2h, row_ptr, col_src, es, ed,
                                                  b2, g2, be2, W3, a3s, a3d,
                                                  h3h, es3, ed3);

    // ---- layer 3 agg + head (fused) ----
    agg3_fused_kernel<<<N_NODES, 64, 0, stream>>>(h3h, row_ptr, col_src, es3, ed3,
                                                  b3, g3, be3, Wh, bh, out);
}

// Round 13
// 373.976 us; speedup vs baseline: 1.0329x; 1.0329x over previous
//
#include <hip/hip_runtime.h>
#include <hip/hip_bf16.h>
#include <math.h>

#define N_NODES 50000
#define E_EDGES 800000
#define ET (E_EDGES + N_NODES)   // edges + self loops = 850000
#define NBLK_SCAN ((N_NODES + 255) / 256)   // 196
#define MPAD 50048               // 391 * 128
#define NPB_T1 16                // nodes per block in transform1
#define WROWS 160                // W2T rows: 128 h2 + 8 attn-dot + 24 pad

typedef __attribute__((ext_vector_type(4))) float f32x4;
typedef __attribute__((ext_vector_type(8))) _Float16 half8;
typedef __attribute__((ext_vector_type(2))) _Float16 half2v;

// ---------------- CSR build ----------------

__global__ void zero_int_kernel(int* __restrict__ p, int n) {
    int i = blockIdx.x * blockDim.x + threadIdx.x;
    if (i < n) p[i] = 0;
}

__global__ void hist_kernel(const int* __restrict__ ei, int* __restrict__ cnt) {
    int e = blockIdx.x * blockDim.x + threadIdx.x;
    if (e < ET) {
        int d = (e < E_EDGES) ? ei[E_EDGES + e] : (e - E_EDGES);
        atomicAdd(&cnt[d], 1);
    }
}

__global__ void scan1_kernel(const int* __restrict__ cnt, int* __restrict__ rp,
                             int* __restrict__ bsum) {
    __shared__ int s[256];
    int i = blockIdx.x * 256 + threadIdx.x;
    int v = (i < N_NODES) ? cnt[i] : 0;
    s[threadIdx.x] = v;
    __syncthreads();
    for (int off = 1; off < 256; off <<= 1) {
        int t = (threadIdx.x >= off) ? s[threadIdx.x - off] : 0;
        __syncthreads();
        s[threadIdx.x] += t;
        __syncthreads();
    }
    if (i < N_NODES) rp[i + 1] = s[threadIdx.x];
    if (threadIdx.x == 255) bsum[blockIdx.x] = s[255];
}

__global__ void scan2_kernel(int* __restrict__ bsum, int nb) {
    __shared__ int s[256];
    int v = (threadIdx.x < nb) ? bsum[threadIdx.x] : 0;
    s[threadIdx.x] = v;
    __syncthreads();
    for (int off = 1; off < 256; off <<= 1) {
        int t = (threadIdx.x >= off) ? s[threadIdx.x - off] : 0;
        __syncthreads();
        s[threadIdx.x] += t;
        __syncthreads();
    }
    if (threadIdx.x < nb) bsum[threadIdx.x] = (threadIdx.x == 0) ? 0 : s[threadIdx.x - 1];
}

__global__ void scan3_kernel(int* __restrict__ rp, const int* __restrict__ bsum,
                             int* __restrict__ cursor) {
    int i = blockIdx.x * 256 + threadIdx.x;
    if (i == 0) rp[0] = 0;
    if (i < N_NODES) {
        int incl = rp[i + 1] + bsum[i >> 8];
        rp[i + 1] = incl;
        cursor[i] = incl - cursor[i];
    }
}

__global__ void fill_kernel(const int* __restrict__ ei, int* __restrict__ cursor,
                            int* __restrict__ col) {
    int e = blockIdx.x * blockDim.x + threadIdx.x;
    if (e < ET) {
        int s_, d;
        if (e < E_EDGES) { s_ = ei[e]; d = ei[E_EDGES + e]; }
        else             { s_ = e - E_EDGES; d = s_; }
        int p = atomicAdd(&cursor[d], 1);
        col[p] = s_;
    }
}

// ---------------- layer-1 specialized path (aggregate in x-space, K=9) ----------------

// es/ed for layer 1, with the 144-entry M table (W1 @ a1s/a1d per input-k) computed
// per block in LDS (L2-hot W1, 9216 FMA/block — trivial; saves a kernel + round-trip).
__global__ __launch_bounds__(256) void es_ed1_kernel(const float* __restrict__ x,
        const float* __restrict__ W1, const float* __restrict__ a1s,
        const float* __restrict__ a1d,
        float* __restrict__ es, float* __restrict__ ed) {
    __shared__ float sM[144];
    int tid = threadIdx.x;
    if (tid < 144) {
        int which = tid / 72, idx = tid % 72, k = idx / 8, h = idx % 8;
        const float* a = which ? a1d : a1s;
        float s = 0.f;
        for (int c = 0; c < 64; c++) s += W1[k * 512 + h * 64 + c] * a[h * 64 + c];
        sM[tid] = s;
    }
    __syncthreads();
    int n = blockIdx.x * 256 + tid;
    if (n >= N_NODES) return;
    float xr[9];
#pragma unroll
    for (int k = 0; k < 9; k++) xr[k] = x[(size_t)n * 9 + k];
#pragma unroll
    for (int h = 0; h < 8; h++) {
        float s1 = 0.f, s2 = 0.f;
#pragma unroll
        for (int k = 0; k < 9; k++) {
            s1 += xr[k] * sM[k * 8 + h];
            s2 += xr[k] * sM[72 + k * 8 + h];
        }
        es[(size_t)n * 8 + h] = s1;
        ed[(size_t)n * 8 + h] = s2;
    }
}

// per-dst: online softmax over in-edges + aggregate x rows (9 floats) per head.
// LDS layout: s_w/s_es e-major with odd/12 stride (conflict-free), float4 es staging,
// 4-deep independent accumulators in the gather.
__global__ __launch_bounds__(128) void agg1_kernel(const float* __restrict__ x,
        const int* __restrict__ rp, const int* __restrict__ col,
        const float* __restrict__ es, const float* __restrict__ ed,
        float* __restrict__ aggx) {
    __shared__ int   s_src[64];
    __shared__ float s_x[64][9];
    __shared__ float s_es[64][12];   // 48B rows: float4-aligned, 2-way banks max
    __shared__ float s_w[64][9];     // e-major, odd stride -> spread banks
    __shared__ float s_m[8], s_den[8], s_scale[8], s_ed[8];
    int n = blockIdx.x, tid = threadIdx.x;
    int start = rp[n], end = rp[n + 1];
    if (tid < 8) { s_m[tid] = -INFINITY; s_den[tid] = 0.f; s_ed[tid] = ed[(size_t)n * 8 + tid]; }
    __syncthreads();
    int ghh = tid >> 4, glane = tid & 15;
    int hh = tid / 9, k = tid - hh * 9;   // valid for tid < 72
    float p0 = 0.f, p1 = 0.f, p2 = 0.f, p3 = 0.f;
    for (int cs = start; cs < end; cs += 64) {
        int cnt = min(64, end - cs);
        if (tid < cnt) s_src[tid] = col[cs + tid];
        __syncthreads();
        for (int q = tid; q < cnt * 9; q += 128) {
            int e = q / 9, kk = q - e * 9;
            s_x[e][kk] = x[(size_t)s_src[e] * 9 + kk];
        }
        for (int q = tid; q < cnt * 2; q += 128) {
            int e = q >> 1, h4 = (q & 1) * 4;
            *(float4*)&s_es[e][h4] = *(const float4*)&es[(size_t)s_src[e] * 8 + h4];
        }
        __syncthreads();
        float lmax = -INFINITY;
        for (int e = glane; e < cnt; e += 16) {
            float l = s_es[e][ghh] + s_ed[ghh];
            l = (l > 0.f) ? l : 0.2f * l;
            s_w[e][ghh] = l;
            lmax = fmaxf(lmax, l);
        }
#pragma unroll
        for (int off = 8; off > 0; off >>= 1) lmax = fmaxf(lmax, __shfl_xor(lmax, off));
        float mold = s_m[ghh];
        float nm = fmaxf(mold, lmax);
        float fac = __expf(mold - nm);
        float psum = 0.f;
        for (int e = glane; e < cnt; e += 16) {
            float w = __expf(s_w[e][ghh] - nm);
            s_w[e][ghh] = w;
            psum += w;
        }
#pragma unroll
        for (int off = 8; off > 0; off >>= 1) psum += __shfl_xor(psum, off);
        if (glane == 0) { s_den[ghh] = s_den[ghh] * fac + psum; s_m[ghh] = nm; s_scale[ghh] = fac; }
        __syncthreads();
        if (tid < 72) {
            float fac2 = s_scale[hh];
            p0 *= fac2; p1 *= fac2; p2 *= fac2; p3 *= fac2;
            int e = 0;
            for (; e + 4 <= cnt; e += 4) {
                p0 += s_w[e][hh]     * s_x[e][k];
                p1 += s_w[e + 1][hh] * s_x[e + 1][k];
                p2 += s_w[e + 2][hh] * s_x[e + 2][k];
                p3 += s_w[e + 3][hh] * s_x[e + 3][k];
            }
            for (; e < cnt; e++) p0 += s_w[e][hh] * s_x[e][k];
        }
        __syncthreads();
    }
    if (tid < 72) {
        aggx[(size_t)n * 72 + tid] = (p0 + p1 + p2 + p3) / s_den[hh];
    }
}

// out = ELU(BN( aggx@W1 + b1 )) -> fp16 [MPAD,512].
__global__ __launch_bounds__(256) void transform1_kernel(const float* __restrict__ aggx,
        const float* __restrict__ W1, const float* __restrict__ b1,
        const float* __restrict__ g1, const float* __restrict__ be1,
        _Float16* __restrict__ Af) {
    __shared__ float s_a[NPB_T1 * 72];
    int tid = threadIdx.x;
    int n0 = blockIdx.x * NPB_T1;
    int nn = min(NPB_T1, N_NODES - n0);
    for (int q = tid; q < nn * 72; q += 256) s_a[q] = aggx[(size_t)n0 * 72 + q];
    int c0 = tid * 2;
    int hh = c0 >> 6;
    float2 wv[9];
#pragma unroll
    for (int k = 0; k < 9; k++) wv[k] = *(const float2*)&W1[k * 512 + c0];
    float2 bv = *(const float2*)&b1[c0];
    float2 gv = *(const float2*)&g1[c0];
    float2 ev = *(const float2*)&be1[c0];
    float gs0 = gv.x / sqrtf(1.00001f), gs1 = gv.y / sqrtf(1.00001f);
    __syncthreads();
    for (int i = 0; i < nn; i++) {
        const float* ar = &s_a[i * 72 + hh * 9];
        float v0 = bv.x, v1 = bv.y;
#pragma unroll
        for (int k = 0; k < 9; k++) { float a = ar[k]; v0 += a * wv[k].x; v1 += a * wv[k].y; }
        v0 = v0 * gs0 + ev.x;
        v1 = v1 * gs1 + ev.y;
        v0 = (v0 > 0.f) ? v0 : expm1f(v0);
        v1 = (v1 > 0.f) ? v1 : expm1f(v1);
        half2v hp;
        hp[0] = (_Float16)v0;
        hp[1] = (_Float16)v1;
        *(half2v*)&Af[(size_t)(n0 + i) * 512 + c0] = hp;
    }
}

// prep: W2^T fp16 [WROWS][512] (rows 0..127 = W2 cols; 128..131 = W2@a2s heads;
// 132..135 = W2@a2d heads).
__global__ void prep2_kernel(const float* __restrict__ W2,
                             const float* __restrict__ a2s, const float* __restrict__ a2d,
                             _Float16* __restrict__ WT) {
    int t = blockIdx.x * 256 + threadIdx.x;
    if (t < 65536) {
        int k = t >> 7, c = t & 127;
        WT[(size_t)c * 512 + k] = (_Float16)W2[t];
    } else if (t < 65536 + 4096) {
        int q = t - 65536;
        int hd8 = q >> 9, k = q & 511;
        const float* a = (hd8 < 4) ? a2s : a2d;
        int hd = hd8 & 3;
        float s = 0.f;
#pragma unroll
        for (int c = 0; c < 32; c++) s += W2[k * 128 + hd * 32 + c] * a[hd * 32 + c];
        WT[(size_t)(128 + hd8) * 512 + k] = (_Float16)s;
    }
}

// ---------------- layer-2 GEMM via fp16 MFMA, fused attn-dot columns ----------------
// R9 128-row version (64-row retile regressed: staging:MFMA ratio halved).
// C[N,136] = A[N,512] @ W2aug; cols 0..127 -> h2 fp16, 128..131 -> es, 132..135 -> ed.

__global__ __launch_bounds__(256) void gemm2_mfma_kernel(
        const _Float16* __restrict__ A, const _Float16* __restrict__ WT,
        _Float16* __restrict__ h2, float* __restrict__ es, float* __restrict__ ed) {
    __shared__ _Float16 ldsA[128 * 64];
    __shared__ _Float16 ldsW[WROWS * 64];
    int tid = threadIdx.x;
    int wv = tid >> 6;
    int lane = tid & 63;
    int lrow = lane & 15, kgrp = lane >> 4;
    int m0 = blockIdx.x * 128;

    f32x4 acc[2][9];
#pragma unroll
    for (int m = 0; m < 2; m++)
#pragma unroll
        for (int n = 0; n < 9; n++) acc[m][n] = (f32x4){0.f, 0.f, 0.f, 0.f};

    for (int kk = 0; kk < 512; kk += 64) {
#pragma unroll
        for (int i = 0; i < 4; i++) {
            int gid = tid + 256 * i;
            int row = gid >> 3, kg = gid & 7;
            half8 v = *(const half8*)(A + (size_t)(m0 + row) * 512 + kk + kg * 8);
            *(half8*)(ldsA + row * 64 + ((kg ^ (row & 7)) << 3)) = v;
        }
#pragma unroll
        for (int i = 0; i < 5; i++) {
            int gid = tid + 256 * i;
            int row = gid >> 3, kg = gid & 7;
            half8 v = *(const half8*)(WT + (size_t)row * 512 + kk + kg * 8);
            *(half8*)(ldsW + row * 64 + ((kg ^ (row & 7)) << 3)) = v;
        }
        __syncthreads();
#pragma unroll
        for (int ks = 0; ks < 2; ks++) {
            int kg = ks * 4 + kgrp;
            half8 af[2];
#pragma unroll
            for (int m = 0; m < 2; m++) {
                int row = wv * 32 + m * 16 + lrow;
                af[m] = *(const half8*)(ldsA + row * 64 + ((kg ^ (row & 7)) << 3));
            }
#pragma unroll
            for (int n = 0; n < 9; n++) {
                int colr = n * 16 + lrow;
                half8 wf = *(const half8*)(ldsW + colr * 64 + ((kg ^ (colr & 7)) << 3));
#pragma unroll
                for (int m = 0; m < 2; m++)
                    acc[m][n] = __builtin_amdgcn_mfma_f32_16x16x32_f16(af[m], wf, acc[m][n], 0, 0, 0);
            }
        }
        __syncthreads();
    }
#pragma unroll
    for (int m = 0; m < 2; m++) {
#pragma unroll
        for (int r = 0; r < 4; r++) {
            int row = m0 + wv * 32 + m * 16 + (lane >> 4) * 4 + r;
            if (row < N_NODES) {
#pragma unroll
                for (int n = 0; n < 8; n++)
                    h2[(size_t)row * 128 + n * 16 + lrow] = (_Float16)acc[m][n][r];
                if (lrow < 4)      es[(size_t)row * 4 + lrow]     = acc[m][8][r];
                else if (lrow < 8) ed[(size_t)row * 4 + lrow - 4] = acc[m][8][r];
            }
        }
    }
}

// ---------------- layer-2 agg (1 wave) + fused layer-3 GEMM + attn dots ----------------
// FROZEN (R8 regression isolation: epilogue rewrite cost +51us at identical counters).

__global__ __launch_bounds__(64) void agg2_fused_kernel(
        const _Float16* __restrict__ hin,
        const int* __restrict__ rp, const int* __restrict__ col,
        const float* __restrict__ es, const float* __restrict__ ed,
        const float* __restrict__ b2, const float* __restrict__ g2,
        const float* __restrict__ be2,
        const float* __restrict__ W3, const float* __restrict__ a3s,
        const float* __restrict__ a3d,
        _Float16* __restrict__ h3, float* __restrict__ es3, float* __restrict__ ed3) {
    constexpr int H = 4, HC = 128, LPH = 16, G = 4, CH = 64;
    __shared__ int   s_src[CH];
    __shared__ float s_w[H][CH];
    __shared__ float s_red[G][HC];
    __shared__ float s_res[HC];
    __shared__ float s_m[H], s_den[H], s_scale[H], s_ed[H];

    int n = blockIdx.x, tid = threadIdx.x;
    int start = rp[n], end = rp[n + 1];
    if (tid < H) { s_m[tid] = -INFINITY; s_den[tid] = 0.f; s_ed[tid] = ed[(size_t)n * H + tid]; }
    __syncthreads();

    int ghh = tid >> 4, glane = tid & 15;      // softmax: 16 lanes per head
    int g = tid >> 4, rl = tid & 15;           // gather: group g, row-lane rl
    int hh2 = rl >> 2;                         // head owning channels rl*8..rl*8+7
    float a0[8], a1[8];
#pragma unroll
    for (int j = 0; j < 8; j++) { a0[j] = 0.f; a1[j] = 0.f; }

    for (int cs = start; cs < end; cs += CH) {
        int cnt = min(CH, end - cs);
        if (tid < cnt) s_src[tid] = col[cs + tid];
        __syncthreads();

        {
            float lmax = -INFINITY;
            for (int e = glane; e < cnt; e += LPH) {
                float l = es[(size_t)s_src[e] * H + ghh] + s_ed[ghh];
                l = (l > 0.f) ? l : 0.2f * l;
                s_w[ghh][e] = l;
                lmax = fmaxf(lmax, l);
            }
#pragma unroll
            for (int off = 8; off > 0; off >>= 1) lmax = fmaxf(lmax, __shfl_xor(lmax, off));
            float mold = s_m[ghh];
            float nm = fmaxf(mold, lmax);
            float fac = __expf(mold - nm);
            float psum = 0.f;
            for (int e = glane; e < cnt; e += LPH) {
                float w = __expf(s_w[ghh][e] - nm);
                s_w[ghh][e] = w;
                psum += w;
            }
#pragma unroll
            for (int off = 8; off > 0; off >>= 1) psum += __shfl_xor(psum, off);
            if (glane == 0) { s_den[ghh] = s_den[ghh] * fac + psum; s_m[ghh] = nm; s_scale[ghh] = fac; }
        }
        __syncthreads();

        {
            float fac = s_scale[hh2];
#pragma unroll
            for (int j = 0; j < 8; j++) a0[j] *= fac;
            int e = g;
            for (; e + G < cnt; e += 2 * G) {
                float w0 = s_w[hh2][e];
                float w1 = s_w[hh2][e + G];
                half8 v0 = *(const half8*)&hin[(size_t)s_src[e] * HC + rl * 8];
                half8 v1 = *(const half8*)&hin[(size_t)s_src[e + G] * HC + rl * 8];
#pragma unroll
                for (int j = 0; j < 8; j++) a0[j] += w0 * (float)v0[j];
#pragma unroll
                for (int j = 0; j < 8; j++) a1[j] += w1 * (float)v1[j];
            }
            if (e < cnt) {
                float w0 = s_w[hh2][e];
                half8 v0 = *(const half8*)&hin[(size_t)s_src[e] * HC + rl * 8];
#pragma unroll
                for (int j = 0; j < 8; j++) a0[j] += w0 * (float)v0[j];
            }
        }
        __syncthreads();
    }

#pragma unroll
    for (int j = 0; j < 8; j++) s_red[g][rl * 8 + j] = a0[j] + a1[j];
    __syncthreads();

    // h2' row: 2 channels per thread, BN+ELU into s_res
    const float rsq = 0.99999499f;   // 1/sqrt(1+1e-5)
#pragma unroll
    for (int half = 0; half < 2; half++) {
        int c = tid + half * 64;
        float r = s_red[0][c] + s_red[1][c] + s_red[2][c] + s_red[3][c];
        r /= s_den[c >> 5];
        r += b2[c];
        r = r * (g2[c] * rsq) + be2[c];
        r = (r > 0.f) ? r : expm1f(r);
        s_res[c] = r;
    }
    __syncthreads();

    // h3 = s_res @ W3 ([128][32], L1-hot): lane (j, half) sums 64 terms, pair-reduce
    int halfk = tid >> 5, j = tid & 31;
    float v = 0.f;
#pragma unroll 16
    for (int c = halfk * 64; c < halfk * 64 + 64; c++) v += s_res[c] * W3[c * 32 + j];
    v += __shfl_xor(v, 32);
    if (tid < 32) h3[(size_t)n * 32 + j] = (_Float16)v;
    // es3/ed3 dots over 32 channels (both halves hold identical v per j)
    float p1 = v * a3s[j], p2 = v * a3d[j];
#pragma unroll
    for (int off = 16; off > 0; off >>= 1) {
        p1 += __shfl_xor(p1, off);
        p2 += __shfl_xor(p2, off);
    }
    if (tid == 0) { es3[n] = p1; ed3[n] = p2; }
}

// ---------------- layer-3 agg (1 wave) + fused head ----------------

__global__ __launch_bounds__(64) void agg3_fused_kernel(
        const _Float16* __restrict__ hin,
        const int* __restrict__ rp, const int* __restrict__ col,
        const float* __restrict__ es3, const float* __restrict__ ed3,
        const float* __restrict__ b3, const float* __restrict__ g3,
        const float* __restrict__ be3,
        const float* __restrict__ Wh, const float* __restrict__ bh,
        float* __restrict__ out) {
    constexpr int G = 16, CH = 64;
    __shared__ int   s_src[CH];
    __shared__ float s_w[CH];
    __shared__ float s_red[G][36];
    __shared__ float s_m1, s_den1, s_scale1, s_ed1;

    int n = blockIdx.x, tid = threadIdx.x;
    int start = rp[n], end = rp[n + 1];
    if (tid == 0) { s_m1 = -INFINITY; s_den1 = 0.f; s_ed1 = ed3[n]; }
    __syncthreads();

    int g = tid >> 2, rl = tid & 3;
    float a0[8], a1[8];
#pragma unroll
    for (int j = 0; j < 8; j++) { a0[j] = 0.f; a1[j] = 0.f; }

    for (int cs = start; cs < end; cs += CH) {
        int cnt = min(CH, end - cs);
        if (tid < cnt) s_src[tid] = col[cs + tid];
        __syncthreads();

        float lmax = -INFINITY;
        float l = 0.f;
        if (tid < cnt) {
            l = es3[s_src[tid]] + s_ed1;
            l = (l > 0.f) ? l : 0.2f * l;
            lmax = l;
        }
#pragma unroll
        for (int off = 32; off > 0; off >>= 1) lmax = fmaxf(lmax, __shfl_xor(lmax, off));
        float mold = s_m1;
        float nm = fmaxf(mold, lmax);
        float fac = __expf(mold - nm);
        float w = 0.f;
        if (tid < cnt) {
            w = __expf(l - nm);
            s_w[tid] = w;
        }
        float psum = w;
#pragma unroll
        for (int off = 32; off > 0; off >>= 1) psum += __shfl_xor(psum, off);
        if (tid == 0) { s_den1 = s_den1 * fac + psum; s_m1 = nm; s_scale1 = fac; }
        __syncthreads();

        {
#pragma unroll
            for (int j = 0; j < 8; j++) a0[j] *= fac;
            int e = g;
            for (; e + G < cnt; e += 2 * G) {
                float w0 = s_w[e];
                float w1 = s_w[e + G];
                half8 v0 = *(const half8*)&hin[(size_t)s_src[e] * 32 + rl * 8];
                half8 v1 = *(const half8*)&hin[(size_t)s_src[e + G] * 32 + rl * 8];
#pragma unroll
                for (int j = 0; j < 8; j++) a0[j] += w0 * (float)v0[j];
#pragma unroll
                for (int j = 0; j < 8; j++) a1[j] += w1 * (float)v1[j];
            }
            if (e < cnt) {
                float w0 = s_w[e];
                half8 v0 = *(const half8*)&hin[(size_t)s_src[e] * 32 + rl * 8];
#pragma unroll
                for (int j = 0; j < 8; j++) a0[j] += w0 * (float)v0[j];
            }
        }
        __syncthreads();
    }

#pragma unroll
    for (int j = 0; j < 8; j++) s_red[g][rl * 8 + j] = a0[j] + a1[j];
    __syncthreads();

    const float rsq = 0.99999499f;
    float p = 0.f;
    if (tid < 32) {
        float r = 0.f;
#pragma unroll
        for (int q = 0; q < G; q++) r += s_red[q][tid];
        r /= s_den1;
        r += b3[tid];
        r = r * (g3[tid] * rsq) + be3[tid];
        r = (r > 0.f) ? r : expm1f(r);
        p = r * Wh[tid];
    }
#pragma unroll
    for (int off = 16; off > 0; off >>= 1) p += __shfl_xor(p, off);
    if (tid == 0) out[n] = p + bh[0];
}

// ---------------- launch ----------------

extern "C" void kernel_launch(void* const* d_in, const int* in_sizes, int n_in,
                              void* d_out, int out_size, void* d_ws, size_t ws_size,
                              hipStream_t stream) {
    const float* x   = (const float*)d_in[0];
    const int*   ei  = (const int*)d_in[1];
    const float* W1  = (const float*)d_in[2];
    const float* a1s = (const float*)d_in[3];
    const float* a1d = (const float*)d_in[4];
    const float* b1  = (const float*)d_in[5];
    const float* W2  = (const float*)d_in[6];
    const float* a2s = (const float*)d_in[7];
    const float* a2d = (const float*)d_in[8];
    const float* b2  = (const float*)d_in[9];
    const float* W3  = (const float*)d_in[10];
    const float* a3s = (const float*)d_in[11];
    const float* a3d = (const float*)d_in[12];
    const float* b3  = (const float*)d_in[13];
    const float* g1  = (const float*)d_in[14];
    const float* be1 = (const float*)d_in[15];
    const float* g2  = (const float*)d_in[16];
    const float* be2 = (const float*)d_in[17];
    const float* g3  = (const float*)d_in[18];
    const float* be3 = (const float*)d_in[19];
    const float* Wh  = (const float*)d_in[20];
    const float* bh  = (const float*)d_in[21];
    float* out = (float*)d_out;

    char* ws = (char*)d_ws;
    size_t off = 0;
    auto alloc = [&](size_t bytes) -> void* {
        void* p = ws + off;
        off += (bytes + 255) & ~(size_t)255;
        return p;
    };
    int*   row_ptr = (int*)alloc((N_NODES + 1) * sizeof(int));
    int*   cursor  = (int*)alloc((N_NODES + 1) * sizeof(int));
    int*   bsum    = (int*)alloc(256 * sizeof(int));
    int*   col_src = (int*)alloc((size_t)ET * sizeof(int));
    float* es      = (float*)alloc((size_t)N_NODES * 8 * sizeof(float));
    float* ed      = (float*)alloc((size_t)N_NODES * 8 * sizeof(float));
    float* es3     = (float*)alloc((size_t)N_NODES * sizeof(float));
    float* ed3     = (float*)alloc((size_t)N_NODES * sizeof(float));
    float* aggx    = (float*)alloc((size_t)N_NODES * 72 * sizeof(float));
    _Float16* h2h  = (_Float16*)alloc((size_t)N_NODES * 128 * sizeof(_Float16));
    _Float16* h3h  = (_Float16*)alloc((size_t)N_NODES * 32 * sizeof(_Float16));
    _Float16* Af   = (_Float16*)alloc((size_t)MPAD * 512 * sizeof(_Float16));
    _Float16* WT   = (_Float16*)alloc((size_t)WROWS * 512 * sizeof(_Float16));

    // ---- CSR build (dst-sorted), shared by all three layers ----
    zero_int_kernel<<<(N_NODES + 1 + 255) / 256, 256, 0, stream>>>(cursor, N_NODES + 1);
    hist_kernel<<<(ET + 255) / 256, 256, 0, stream>>>(ei, cursor);
    scan1_kernel<<<NBLK_SCAN, 256, 0, stream>>>(cursor, row_ptr, bsum);
    scan2_kernel<<<1, 256, 0, stream>>>(bsum, NBLK_SCAN);
    scan3_kernel<<<NBLK_SCAN, 256, 0, stream>>>(row_ptr, bsum, cursor);
    fill_kernel<<<(ET + 255) / 256, 256, 0, stream>>>(ei, cursor, col_src);

    // ---- layer 1: GAT(9 -> 8x64, concat) + BN + ELU, aggregated in x-space ----
    es_ed1_kernel<<<(N_NODES + 255) / 256, 256, 0, stream>>>(x, W1, a1s, a1d, es, ed);
    agg1_kernel<<<N_NODES, 128, 0, stream>>>(x, row_ptr, col_src, es, ed, aggx);
    transform1_kernel<<<(N_NODES + NPB_T1 - 1) / NPB_T1, 256, 0, stream>>>(aggx, W1, b1, g1, be1, Af);

    // ---- layer 2: fp16 MFMA GEMM with fused attn-dot cols, then agg (+layer-3 prep) ----
    prep2_kernel<<<288, 256, 0, stream>>>(W2, a2s, a2d, WT);
    gemm2_mfma_kernel<<<MPAD / 128, 256, 0, stream>>>(Af, WT, h2h, es, ed);
    agg2_fused_kernel<<<N_NODES, 64, 0, stream>>>(h2h, row_ptr, col_src, es, ed,
                                                  b2, g2, be2, W3, a3s, a3d,
                                                  h3h, es3, ed3);

    // ---- layer 3 agg + head (fused) ----
    agg3_fused_kernel<<<N_NODES, 64, 0, stream>>>(h3h, row_ptr, col_src, es3, ed3,
                                                  b3, g3, be3, Wh, bh, out);
}